// Round 6
// baseline (252.080 us; speedup 1.0000x reference)
//
#include <hip/hip_runtime.h>

// Frame-wise E^H D E exact NDFT via separable phasors as two complex GEMMs on
// fp16 matrix cores (fp32 accumulate).
// v7 = v6 (244.9us) + fwd re-tiled for traffic/occupancy, adj untouched:
//  - fwd_gemm: kp-tile 64 -> 128 via 512 thr (8 waves: 2 mh x 4 nq). Per-wave
//    tile/acc unchanged (64 VGPR acc). A re-read factor halves (32->16),
//    total fwd read traffic 512 -> 384 MB; 2-3 blocks/CU instead of 2.
//    Grid reordered c-fastest (t slowest) so same-(t,kt) blocks share B/Ey
//    tiles while L2/L3-hot.
//  - adj_gemm: v0 body verbatim (95us proven); only launch order swapped to
//    yt-fastest so same-t blocks share the ExT slice temporally.
//  - preps: unchanged from v6.

#define NT 16
#define NK 2048
#define NXY 128
#define NC 8

typedef _Float16 f16x8 __attribute__((ext_vector_type(8)));
typedef float f32x4 __attribute__((ext_vector_type(4)));

union F8 { f16x8 h; uint u[4]; };

#define MFMA16(a, b, c) __builtin_amdgcn_mfma_f32_16x16x32_f16((a), (b), (c), 0, 0, 0)

__device__ __forceinline__ uint pack2h(float a, float b) {
    union { _Float16 h[2]; uint u; } p;
    p.h[0] = (_Float16)a; p.h[1] = (_Float16)b;
    return p.u;
}
__device__ __forceinline__ float2 unpack2h(uint v) {
    union { uint u; _Float16 h[2]; } p;
    p.u = v;
    return make_float2((float)p.h[0], (float)p.h[1]);
}
__device__ __forceinline__ uint rot16(uint v) { return (v >> 16) | (v << 16); }

// ---------------------------------------------------------------------------
// prep_phasA: tiled ExC [t][kt16][xc8][kp128][xq16] (fwd main-loop B) and
// linear EyL [t][k][y] (adj build + fwd epilogue). exp(-i*k*(coord-64)).
// ---------------------------------------------------------------------------
__global__ __launch_bounds__(256) void prep_phasA(const float* __restrict__ ktraj,
                                                  uint* __restrict__ ExC,
                                                  uint* __restrict__ EyL) {
    const int t = blockIdx.x;
    const int k = blockIdx.y * 2 + (threadIdx.x >> 7);
    const int x = threadIdx.x & 127;
    const float kx = ktraj[(size_t)k * NT + t];
    const float ky = ktraj[(size_t)(NK + k) * NT + t];
    const float xm = (float)(x - 64);
    float s, c;
    __sincosf(-kx * xm, &s, &c);
    ExC[((size_t)(t * 16 + (k >> 7)) * 8 + (x >> 4)) * 2048 +
        (size_t)(k & 127) * 16 + (x & 15)] = pack2h(c, s);
    __sincosf(-ky * xm, &s, &c);
    EyL[((size_t)t * NK + k) * NXY + x] = pack2h(c, s);
}

// ---------------------------------------------------------------------------
// ExT[t][x][k]; lanes = k -> contiguous 1KB store runs. (adj B-loads)
// ---------------------------------------------------------------------------
__global__ __launch_bounds__(256) void prep_phasB(const float* __restrict__ ktraj,
                                                  uint* __restrict__ ExT) {
    const int t = blockIdx.x, x = blockIdx.y;
    const int k = blockIdx.z * 256 + threadIdx.x;
    const float kx = ktraj[(size_t)k * NT + t];
    float s, c;
    __sincosf(-kx * (float)(x - 64), &s, &c);
    ExT[((size_t)t * NXY + x) * NK + k] = pack2h(c, s);
}

// ---------------------------------------------------------------------------
// srcB in MFMA-fragment order: [t][c][ch8][mf8][r16][xl16] dwords,
// element = smap[c,x,y]*img[x,y,t], x = ch*16+xl, y = mf*16+r.
// ---------------------------------------------------------------------------
__global__ __launch_bounds__(256) void prep_src(const float* __restrict__ xin,
                                                const float* __restrict__ csmap,
                                                uint* __restrict__ srcB) {
    const int idx = blockIdx.x * 256 + threadIdx.x;   // < 2^21
    const int t = idx & 15, r = (idx >> 4) & 15, xl = (idx >> 8) & 15,
              mf = (idx >> 12) & 7, ch = (idx >> 15) & 7, c = idx >> 18;
    const int x = ch * 16 + xl, y = mf * 16 + r;
    const float ir = xin[(size_t)(x * NXY + y) * NT + t];
    const float ii = xin[(size_t)NXY * NXY * NT + (size_t)(x * NXY + y) * NT + t];
    const float sr = csmap[(size_t)c * 2 * NXY * NXY + x * NXY + y];
    const float si = csmap[(size_t)c * 2 * NXY * NXY + NXY * NXY + x * NXY + y];
    srcB[((size_t)(t * NC + c) << 14) + ch * 2048 + mf * 256 + r * 16 + xl] =
        pack2h(sr * ir - si * ii, sr * ii + si * ir);
}

// ---------------------------------------------------------------------------
// fwd_gemm: block = (c, kt of 128 kpoints, t), 512 thr (8 waves: 2 mh x 4 nq).
// C1[y=128, kp=128] over K'=256, 8 chunks of 16 x-dwords. Fragment-ordered
// LDS A (contiguous stage/read), B + A prefetched one chunk ahead in regs.
// Per-wave tile 64y x 32kp -> acc 64 VGPR (v6's proven shape).
// ---------------------------------------------------------------------------
__global__ __launch_bounds__(512, 2) void fwd_gemm(const uint* __restrict__ ExC,
                                                   const uint* __restrict__ EyL,
                                                   const uint* __restrict__ srcB,
                                                   const float* __restrict__ dcomp,
                                                   float2* __restrict__ g) {
    const int c = blockIdx.x, kt = blockIdx.y, t = blockIdx.z;
    const int tid = threadIdx.x, lane = tid & 63, ws = tid >> 6;
    const int quad = lane >> 4, l15 = lane & 15;
    const int mh = ws >> 2, nq = ws & 3;

    __shared__ __align__(16) _Float16 As[2][4096];

    f32x4 accr[4][2], acci[4][2];
#pragma unroll
    for (int mf = 0; mf < 4; ++mf)
#pragma unroll
        for (int nf = 0; nf < 2; ++nf) { accr[mf][nf] = (f32x4)0.0f; acci[mf][nf] = (f32x4)0.0f; }

    const uint* srcT = srcB + ((size_t)(t * NC + c) << 14);
    const uint* exB = ExC + (size_t)(t * 16 + kt) * 16384;
    const int kin0 = nq * 32;                            // kp base within 128-tile

    // prologue: stage + B loads for chunk 0
    F8 vA0 = *(const F8*)(srcT + tid * 4);
    F8 Bc0 = *(const F8*)(exB + (kin0 + l15) * 16 + quad * 4);
    F8 Bc1 = *(const F8*)(exB + (kin0 + 16 + l15) * 16 + quad * 4);

#pragma unroll 2
    for (int ch = 0; ch < 8; ++ch) {
        const int buf = ch & 1;
        *(F8*)&As[buf][tid * 8] = vA0;
        __syncthreads();
        const int chn = ch < 7 ? ch + 1 : 7;
        vA0 = *(const F8*)(srcT + chn * 2048 + tid * 4);
        F8 Bn0 = *(const F8*)(exB + chn * 2048 + (kin0 + l15) * 16 + quad * 4);
        F8 Bn1 = *(const F8*)(exB + chn * 2048 + (kin0 + 16 + l15) * 16 + quad * 4);
        __builtin_amdgcn_sched_barrier(0);
#pragma unroll
        for (int mf = 0; mf < 4; ++mf) {
            F8 Ap = *(const F8*)&As[buf][(mh * 4 + mf) * 512 + l15 * 32 + quad * 8];
            F8 Ar, Ai;
#pragma unroll
            for (int d = 0; d < 4; ++d) {
                Ar.u[d] = Ap.u[d] ^ 0x80000000u;   // (sR, -sI)
                Ai.u[d] = rot16(Ap.u[d]);          // (sI,  sR)
            }
            accr[mf][0] = MFMA16(Ar.h, Bc0.h, accr[mf][0]);
            acci[mf][0] = MFMA16(Ai.h, Bc0.h, acci[mf][0]);
            accr[mf][1] = MFMA16(Ar.h, Bc1.h, accr[mf][1]);
            acci[mf][1] = MFMA16(Ai.h, Bc1.h, acci[mf][1]);
        }
        Bc0 = Bn0; Bc1 = Bn1;
    }

    // epilogue: partial y-reduction with Ey (linear layout) per mh-half, LDS combine
    __syncthreads();
    float* red = (float*)(&As[0][0]);          // 2*128*2 floats
#pragma unroll
    for (int nf = 0; nf < 2; ++nf) {
        const int kin = kin0 + nf * 16 + l15;                   // kp within 128-tile
        const int kpoint = kt * 128 + kin;
        const uint* eyRow = EyL + ((size_t)t * NK + kpoint) * NXY;
        float kdr = 0.f, kdi = 0.f;
#pragma unroll
        for (int mf = 0; mf < 4; ++mf) {
            const int yc = mh * 4 + mf;
            F8 e4 = *(const F8*)(eyRow + yc * 16 + quad * 4);
#pragma unroll
            for (int rr = 0; rr < 4; ++rr) {
                float2 ey = unpack2h(e4.u[rr]);
                float cr = accr[mf][nf][rr], ci = acci[mf][nf][rr];
                kdr += ey.x * cr - ey.y * ci;
                kdi += ey.x * ci + ey.y * cr;
            }
        }
        kdr += __shfl_xor(kdr, 16); kdr += __shfl_xor(kdr, 32);
        kdi += __shfl_xor(kdi, 16); kdi += __shfl_xor(kdi, 32);
        if (lane < 16) {
            const int kl = nq * 32 + nf * 16 + l15;       // 0..127
            red[(mh * 128 + kl) * 2] = kdr;
            red[(mh * 128 + kl) * 2 + 1] = kdi;
        }
    }
    __syncthreads();
    if (tid < 128) {
        const int kpoint = kt * 128 + tid;
        const float kdr = red[tid * 2] + red[(128 + tid) * 2];
        const float kdi = red[tid * 2 + 1] + red[(128 + tid) * 2 + 1];
        const float w = dcomp[(size_t)kpoint * NT + t] * (1.0f / 16384.0f);
        g[((size_t)t * NK + kpoint) * NC + c] = make_float2(kdr * w, kdi * w);
    }
}

// ---------------------------------------------------------------------------
// adj_gemm: block = (ytile of 8 y, t), 512 thr (8 waves).  (v0 body VERBATIM)
// GEMM C3[m=(yloc*8+c)=64, x(n)=128] over K'=4096 (kpoints interleaved r/i),
// chunks of 64 halves (32 kpoints). A = t2 = conj(Ey)*g built in LDS ping-pong;
// B = ExT rows (global). Epilogue: coil-combine with conj(smap) -> out.
// ---------------------------------------------------------------------------
__global__ __launch_bounds__(512) void adj_gemm(const uint* __restrict__ ExT,
                                                const uint* __restrict__ EyL,
                                                const float2* __restrict__ g,
                                                const float* __restrict__ csmap,
                                                float* __restrict__ out) {
    const int yt = blockIdx.x, t = blockIdx.y, ybase = yt * 8;
    const int tid = threadIdx.x, lane = tid & 63, ws = tid >> 6;
    const int quad = lane >> 4, l15 = lane & 15;
    const int x = ws * 16 + l15;

    __shared__ __align__(16) _Float16 Ts[2][64][72];    // 64 K'-halves + 8 pad

    f32x4 accr[4], acci[4];
#pragma unroll
    for (int mf = 0; mf < 4; ++mf) { accr[mf] = (f32x4)0.0f; acci[mf] = (f32x4)0.0f; }

    const float2* gBase = g + (size_t)t * NK * NC;
    const uint* eyBase = EyL + (size_t)t * NK * NXY;
    const uint* exBase = ExT + (size_t)t * NXY * NK;

    const int bm = tid & 63;                 // build: row m
    const int bk4 = (tid >> 6) * 4;          // build: kpoint offset (0..28)
    const int by = ybase + (bm >> 3), bc = bm & 7;

    // build chunk 0
    {
        F8 w;
#pragma unroll
        for (int j = 0; j < 4; ++j) {
            int kp = bk4 + j;
            float2 gv = gBase[kp * NC + bc];
            float2 ey = unpack2h(eyBase[(size_t)kp * NXY + by]);
            w.u[j] = pack2h(ey.x * gv.x + ey.y * gv.y, ey.x * gv.y - ey.y * gv.x);
        }
        *(F8*)&Ts[0][bm][bk4 * 2] = w;
    }
    __syncthreads();

    for (int ch = 0; ch < 64; ++ch) {
        const int buf = ch & 1;
#pragma unroll
        for (int ks = 0; ks < 2; ++ks) {
            const int kp = ch * 32 + ks * 16 + quad * 4;
            F8 Bf = *(const F8*)(exBase + (size_t)x * NK + kp);
#pragma unroll
            for (int mf = 0; mf < 4; ++mf) {
                F8 Ap = *(const F8*)&Ts[buf][mf * 16 + l15][ks * 32 + quad * 8];
                F8 Ai;
#pragma unroll
                for (int d = 0; d < 4; ++d) Ai.u[d] = rot16(Ap.u[d]) ^ 0x80000000u; // (t2I, -t2R)
                accr[mf] = MFMA16(Ap.h, Bf.h, accr[mf]);
                acci[mf] = MFMA16(Ai.h, Bf.h, acci[mf]);
            }
        }
        if (ch < 63) {
            F8 w;
#pragma unroll
            for (int j = 0; j < 4; ++j) {
                int kp = (ch + 1) * 32 + bk4 + j;
                float2 gv = gBase[kp * NC + bc];
                float2 ey = unpack2h(eyBase[(size_t)kp * NXY + by]);
                w.u[j] = pack2h(ey.x * gv.x + ey.y * gv.y, ey.x * gv.y - ey.y * gv.x);
            }
            *(F8*)&Ts[buf ^ 1][bm][bk4 * 2] = w;
        }
        __syncthreads();
    }

    // epilogue: coil-combine with conj(smap), write out[2][x][y][t]
#pragma unroll
    for (int mf = 0; mf < 4; ++mf) {
        const int y = ybase + 2 * mf + (quad >> 1);
        float or_ = 0.f, oi_ = 0.f;
#pragma unroll
        for (int r = 0; r < 4; ++r) {
            int c = 4 * (quad & 1) + r;
            float sr = csmap[(size_t)c * 2 * NXY * NXY + x * NXY + y];
            float si = csmap[(size_t)c * 2 * NXY * NXY + NXY * NXY + x * NXY + y];
            float xr = accr[mf][r], xi = acci[mf][r];
            or_ += sr * xr + si * xi;
            oi_ += sr * xi - si * xr;
        }
        or_ += __shfl_xor(or_, 16);
        oi_ += __shfl_xor(oi_, 16);
        if ((lane & 16) == 0) {
            out[(size_t)(x * NXY + y) * NT + t] = or_;
            out[(size_t)NXY * NXY * NT + (size_t)(x * NXY + y) * NT + t] = oi_;
        }
    }
}

// ---------------------------------------------------------------------------
extern "C" void kernel_launch(void* const* d_in, const int* in_sizes, int n_in,
                              void* d_out, int out_size, void* d_ws, size_t ws_size,
                              hipStream_t stream) {
    const float* xin   = (const float*)d_in[0];  // (2,128,128,16)
    const float* ktraj = (const float*)d_in[1];  // (2,2048,16)
    const float* csmap = (const float*)d_in[2];  // (8,2,128,128)
    const float* dcomp = (const float*)d_in[3];  // (2048,16)
    float* out = (float*)d_out;                  // (2,128,128,16)

    // ws layout: ExC + ExT + EyL (16MB each) + srcB 8MB + g 2MB = 58MB
    const size_t TBL = (size_t)NT * NK * NXY;            // 4.19M dwords per table
    uint* ExC  = (uint*)d_ws;                            // [t][kt][xc][kp][xq]
    uint* ExT  = ExC + TBL;                              // [t][x][k]
    uint* EyL  = ExT + TBL;                              // [t][k][y]
    uint* srcB = EyL + TBL;                              // fragment-ordered
    float2* g  = (float2*)(srcB + (size_t)NT * NC * NXY * NXY);  // [t][k][c]

    prep_phasA<<<dim3(NT, NK / 2), 256, 0, stream>>>(ktraj, ExC, EyL);
    prep_phasB<<<dim3(NT, NXY, NK / 256), 256, 0, stream>>>(ktraj, ExT);
    prep_src<<<dim3(8192), 256, 0, stream>>>(xin, csmap, srcB);
    fwd_gemm<<<dim3(NC, 16, NT), 512, 0, stream>>>(ExC, EyL, srcB, dcomp, g);
    adj_gemm<<<dim3(NXY / 8, NT), 512, 0, stream>>>(ExT, EyL, g, csmap, out);
}